// Round 12
// baseline (128.237 us; speedup 1.0000x reference)
//
#include <hip/hip_runtime.h>
#include <math.h>

#define NP 128       // patches per side
#define NB 32        // batch (light dirs)

typedef float vf4 __attribute__((ext_vector_type(4)));  // native 16B vector

// ---------------------------------------------------------------------------
// Kernel A: one thread per (b, patch): MLP -> color[b][p][3] f32 in ws (6MB).
// p in low bits -> wave-contiguous 768B color stores.
// ---------------------------------------------------------------------------
__global__ __launch_bounds__(256) void mlp_colors(
    const float* __restrict__ ld,   // [32][2]
    const float* __restrict__ w1,   // [p][8][2]
    const float* __restrict__ b1,   // [p][8]
    const float* __restrict__ w2,   // [p][8][8]
    const float* __restrict__ b2,   // [p][8]
    const float* __restrict__ w3,   // [p][8][8]
    const float* __restrict__ b3,   // [p][8]
    const float* __restrict__ wo,   // [p][3][8]
    const float* __restrict__ bo,   // [p][3]
    float* __restrict__ color)      // [32][16384][3]
{
    unsigned int tid = blockIdx.x * blockDim.x + threadIdx.x;  // 0 .. 524287
    int p = tid & 16383;
    int b = tid >> 14;

    float x0 = ld[2 * b + 0];
    float x1 = ld[2 * b + 1];

    float h[8], g[8];
    {   // layer 1: 2 -> 8
        const float* W  = w1 + (size_t)p * 16;
        const float* Bv = b1 + (size_t)p * 8;
#pragma unroll
        for (int o = 0; o < 8; ++o) {
            float s = fmaf(W[2 * o + 0], x0, fmaf(W[2 * o + 1], x1, Bv[o]));
            h[o] = fmaxf(0.f, s);
        }
    }
    {   // layer 2: 8 -> 8
        const float* W  = w2 + (size_t)p * 64;
        const float* Bv = b2 + (size_t)p * 8;
#pragma unroll
        for (int o = 0; o < 8; ++o) {
            float s = Bv[o];
#pragma unroll
            for (int i = 0; i < 8; ++i) s = fmaf(W[8 * o + i], h[i], s);
            g[o] = fmaxf(0.f, s);
        }
    }
    {   // layer 3: 8 -> 8
        const float* W  = w3 + (size_t)p * 64;
        const float* Bv = b3 + (size_t)p * 8;
#pragma unroll
        for (int o = 0; o < 8; ++o) {
            float s = Bv[o];
#pragma unroll
            for (int i = 0; i < 8; ++i) s = fmaf(W[8 * o + i], g[i], s);
            h[o] = fmaxf(0.f, s);
        }
    }
    {   // out layer: 8 -> 3, sigmoid
        const float* W  = wo + (size_t)p * 24;
        const float* Bv = bo + (size_t)p * 3;
        float* cp = color + ((size_t)b * 16384 + (size_t)p) * 3;
#pragma unroll
        for (int c = 0; c < 3; ++c) {
            float s = Bv[c];
#pragma unroll
            for (int i = 0; i < 8; ++i) s = fmaf(W[8 * c + i], h[i], s);
            cp[c] = 1.f / (1.f + expf(-s));
        }
    }
}

// ---------------------------------------------------------------------------
// Kernel B: pure broadcast writer (round-10's proven store loop).
// One block per (b, ph): LDS <- 384 floats from ws, then 24 NT float4 stores
// per thread, c = k*256 + t (1KB contiguous per wave instruction).
// ---------------------------------------------------------------------------
__global__ __launch_bounds__(256) void tile_write_f32(
    const float* __restrict__ color,  // [32][16384][3]
    float* __restrict__ out)          // [32][1024][1024][3]
{
    int bid = blockIdx.x;        // 0 .. 4095 = b*128 + ph
    int t = threadIdx.x;         // 0 .. 255

    __shared__ float cl[NP * 3];  // 384 floats

    const float* src = color + (size_t)bid * (NP * 3);
    cl[t] = src[t >= 384 ? 0 : t];          // t<256 always valid
    if (t < 128) cl[256 + t] = src[256 + t];
    __syncthreads();

    // block's slab: 8 rows * 768 float4 = 6144 chunks, base = bid*6144
    vf4* op = (vf4*)out + (size_t)bid * 6144;

#pragma unroll
    for (int k = 0; k < 24; ++k) {
        int c  = k * 256 + t;         // 0 .. 6143
        int row = c / 768;            // 0..7 (identical data each row)
        int ct = c - row * 768;       // 0..767
        int pw = ct / 6;              // patch col
        int s  = ct % 3;              // first channel in this chunk

        float c0 = cl[pw * 3 + 0];
        float c1 = cl[pw * 3 + 1];
        float c2 = cl[pw * 3 + 2];
        float ca = (s == 0) ? c0 : ((s == 1) ? c1 : c2);
        float cb = (s == 0) ? c1 : ((s == 1) ? c2 : c0);
        float cc = (s == 0) ? c2 : ((s == 1) ? c0 : c1);

        vf4 v;
        v.x = ca; v.y = cb; v.z = cc; v.w = ca;
        __builtin_nontemporal_store(v, &op[c]);
    }
}

// ---------------------------------------------------------------------------
// Fallback: round-10 fused kernel (95.8 µs proven) if ws is too small.
// ---------------------------------------------------------------------------
__global__ __launch_bounds__(256) void fused_relight(
    const float* __restrict__ ld, const float* __restrict__ w1,
    const float* __restrict__ b1, const float* __restrict__ w2,
    const float* __restrict__ b2, const float* __restrict__ w3,
    const float* __restrict__ b3, const float* __restrict__ wo,
    const float* __restrict__ bo, float* __restrict__ out)
{
    int bid = blockIdx.x;
    int ph = bid >> 5;
    int b  = bid & 31;
    int t  = threadIdx.x;

    __shared__ float cl[NP * 3];

    if (t < NP) {
        int p = ph * NP + t;
        float x0 = ld[2 * b + 0];
        float x1 = ld[2 * b + 1];
        float h[8], g[8];
        {
            const float* W  = w1 + (size_t)p * 16;
            const float* Bv = b1 + (size_t)p * 8;
#pragma unroll
            for (int o = 0; o < 8; ++o)
                h[o] = fmaxf(0.f, fmaf(W[2*o], x0, fmaf(W[2*o+1], x1, Bv[o])));
        }
        {
            const float* W  = w2 + (size_t)p * 64;
            const float* Bv = b2 + (size_t)p * 8;
#pragma unroll
            for (int o = 0; o < 8; ++o) {
                float s = Bv[o];
#pragma unroll
                for (int i = 0; i < 8; ++i) s = fmaf(W[8*o+i], h[i], s);
                g[o] = fmaxf(0.f, s);
            }
        }
        {
            const float* W  = w3 + (size_t)p * 64;
            const float* Bv = b3 + (size_t)p * 8;
#pragma unroll
            for (int o = 0; o < 8; ++o) {
                float s = Bv[o];
#pragma unroll
                for (int i = 0; i < 8; ++i) s = fmaf(W[8*o+i], g[i], s);
                h[o] = fmaxf(0.f, s);
            }
        }
        {
            const float* W  = wo + (size_t)p * 24;
            const float* Bv = bo + (size_t)p * 3;
#pragma unroll
            for (int c = 0; c < 3; ++c) {
                float s = Bv[c];
#pragma unroll
                for (int i = 0; i < 8; ++i) s = fmaf(W[8*c+i], h[i], s);
                cl[t * 3 + c] = 1.f / (1.f + expf(-s));
            }
        }
    }
    __syncthreads();

    vf4* op = (vf4*)out + (size_t)b * 786432 + (size_t)ph * 6144;
#pragma unroll
    for (int k = 0; k < 24; ++k) {
        int c  = k * 256 + t;
        int row = c / 768;
        int ct = c - row * 768;
        int pw = ct / 6;
        int s  = ct % 3;
        float c0 = cl[pw * 3 + 0];
        float c1 = cl[pw * 3 + 1];
        float c2 = cl[pw * 3 + 2];
        float ca = (s == 0) ? c0 : ((s == 1) ? c1 : c2);
        float cb = (s == 0) ? c1 : ((s == 1) ? c2 : c0);
        float cc = (s == 0) ? c2 : ((s == 1) ? c0 : c1);
        vf4 v; v.x = ca; v.y = cb; v.z = cc; v.w = ca;
        __builtin_nontemporal_store(v, &op[c]);
    }
}

extern "C" void kernel_launch(void* const* d_in, const int* in_sizes, int n_in,
                              void* d_out, int out_size, void* d_ws, size_t ws_size,
                              hipStream_t stream) {
    const float* ld = (const float*)d_in[0];
    const float* w1 = (const float*)d_in[1];
    const float* b1 = (const float*)d_in[2];
    const float* w2 = (const float*)d_in[3];
    const float* b2 = (const float*)d_in[4];
    const float* w3 = (const float*)d_in[5];
    const float* b3 = (const float*)d_in[6];
    const float* wo = (const float*)d_in[7];
    const float* bo = (const float*)d_in[8];

    float* out = (float*)d_out;
    const size_t color_bytes = (size_t)NB * NP * NP * 3 * sizeof(float);  // 6MB

    if (ws_size >= color_bytes) {
        float* color = (float*)d_ws;
        mlp_colors<<<dim3((NB * NP * NP) / 256), dim3(256), 0, stream>>>(
            ld, w1, b1, w2, b2, w3, b3, wo, bo, color);
        tile_write_f32<<<dim3(NB * NP), dim3(256), 0, stream>>>(color, out);
    } else {
        fused_relight<<<dim3(NP * NB), dim3(256), 0, stream>>>(
            ld, w1, b1, w2, b2, w3, b3, wo, bo, out);
    }
}

// Round 13
// 100.555 us; speedup vs baseline: 1.2753x; 1.2753x over previous
//
#include <hip/hip_runtime.h>
#include <math.h>

#define NP 128       // patches per side
#define NB 32        // batch (light dirs)

typedef float vf4 __attribute__((ext_vector_type(4)));  // native 16B vector

// ---------------------------------------------------------------------------
// Fused (round-10 base, 95.8us proven) with phase-2 values HOISTED:
//  phase 1: threads 0..127 run the MLP for patch (ph, t), 3 f32 colors -> LDS.
//  phase 2: thread t owns chunks {t, t+256, t+512} of the 768-chunk row
//           pattern; computes the 3 float4 values ONCE, then stores each 8x
//           (rows identical) with the exact same NT-store address sequence
//           as round 10 (c = (row*3+j)*256 + t).
// ---------------------------------------------------------------------------
__global__ __launch_bounds__(256) void fused_relight(
    const float* __restrict__ ld,   // [32][2]
    const float* __restrict__ w1,   // [p][8][2]
    const float* __restrict__ b1,   // [p][8]
    const float* __restrict__ w2,   // [p][8][8]
    const float* __restrict__ b2,   // [p][8]
    const float* __restrict__ w3,   // [p][8][8]
    const float* __restrict__ b3,   // [p][8]
    const float* __restrict__ wo,   // [p][3][8]
    const float* __restrict__ bo,   // [p][3]
    float* __restrict__ out)        // [32][1024][1024][3] f32
{
    int bid = blockIdx.x;        // 0 .. 4095
    int ph = bid >> 5;           // patch row
    int b  = bid & 31;           // light index
    int t  = threadIdx.x;        // 0 .. 255

    __shared__ float cl[NP * 3];  // 384 floats

    if (t < NP) {
        int p = ph * NP + t;     // patch id
        float x0 = ld[2 * b + 0];
        float x1 = ld[2 * b + 1];

        float h[8], g[8];
        {   // layer 1: 2 -> 8
            const float* W  = w1 + (size_t)p * 16;
            const float* Bv = b1 + (size_t)p * 8;
#pragma unroll
            for (int o = 0; o < 8; ++o) {
                float s = fmaf(W[2 * o + 0], x0, fmaf(W[2 * o + 1], x1, Bv[o]));
                h[o] = fmaxf(0.f, s);
            }
        }
        {   // layer 2: 8 -> 8
            const float* W  = w2 + (size_t)p * 64;
            const float* Bv = b2 + (size_t)p * 8;
#pragma unroll
            for (int o = 0; o < 8; ++o) {
                float s = Bv[o];
#pragma unroll
                for (int i = 0; i < 8; ++i) s = fmaf(W[8 * o + i], h[i], s);
                g[o] = fmaxf(0.f, s);
            }
        }
        {   // layer 3: 8 -> 8
            const float* W  = w3 + (size_t)p * 64;
            const float* Bv = b3 + (size_t)p * 8;
#pragma unroll
            for (int o = 0; o < 8; ++o) {
                float s = Bv[o];
#pragma unroll
                for (int i = 0; i < 8; ++i) s = fmaf(W[8 * o + i], g[i], s);
                h[o] = fmaxf(0.f, s);
            }
        }
        {   // out layer: 8 -> 3, sigmoid -> LDS
            const float* W  = wo + (size_t)p * 24;
            const float* Bv = bo + (size_t)p * 3;
#pragma unroll
            for (int c = 0; c < 3; ++c) {
                float s = Bv[c];
#pragma unroll
                for (int i = 0; i < 8; ++i) s = fmaf(W[8 * c + i], h[i], s);
                cl[t * 3 + c] = 1.f / (1.f + expf(-s));
            }
        }
    }
    __syncthreads();

    // Phase 2: compute this thread's 3 chunk values once.
    // Chunk ct (0..767): patch pw = ct/6, start channel s = ct%3,
    // value = [s, s+1, s+2, s] (mod 3) of that patch's color.
    vf4 v[3];
#pragma unroll
    for (int j = 0; j < 3; ++j) {
        int ct = j * 256 + t;         // 0..767
        int pw = ct / 6;
        int s  = ct % 3;

        float c0 = cl[pw * 3 + 0];
        float c1 = cl[pw * 3 + 1];
        float c2 = cl[pw * 3 + 2];
        float ca = (s == 0) ? c0 : ((s == 1) ? c1 : c2);
        float cb = (s == 0) ? c1 : ((s == 1) ? c2 : c0);
        float cc = (s == 0) ? c2 : ((s == 1) ? c0 : c1);

        v[j].x = ca; v[j].y = cb; v[j].z = cc; v[j].w = ca;
    }

    // Same address sequence as round 10: c = (row*3+j)*256 + t.
    vf4* op = (vf4*)out + (size_t)b * 786432 + (size_t)ph * 6144;
#pragma unroll
    for (int row = 0; row < 8; ++row) {
        __builtin_nontemporal_store(v[0], &op[row * 768 + t]);
        __builtin_nontemporal_store(v[1], &op[row * 768 + 256 + t]);
        __builtin_nontemporal_store(v[2], &op[row * 768 + 512 + t]);
    }
}

extern "C" void kernel_launch(void* const* d_in, const int* in_sizes, int n_in,
                              void* d_out, int out_size, void* d_ws, size_t ws_size,
                              hipStream_t stream) {
    const float* ld = (const float*)d_in[0];
    const float* w1 = (const float*)d_in[1];
    const float* b1 = (const float*)d_in[2];
    const float* w2 = (const float*)d_in[3];
    const float* b2 = (const float*)d_in[4];
    const float* w3 = (const float*)d_in[5];
    const float* b3 = (const float*)d_in[6];
    const float* wo = (const float*)d_in[7];
    const float* bo = (const float*)d_in[8];

    float* out = (float*)d_out;

    fused_relight<<<dim3(NP * NB), dim3(256), 0, stream>>>(
        ld, w1, b1, w2, b2, w3, b3, wo, bo, out);
}